// Round 18
// baseline (2451.563 us; speedup 1.0000x reference)
//
#include <hip/hip_runtime.h>
#include <hip/hip_bf16.h>

#define T_LEN 512
#define NB 64      // batch
#define FB 256     // input features
#define SB 1024    // hidden size
#define NWG 256    // persistent workgroups: (ng 0..3) x (sb 0..63)

#define SENT32 0x7FC07FC0u
#define SENT64 0x7FC07FC07FC07FC0ULL

typedef __attribute__((ext_vector_type(8))) short bf16x8;
typedef __attribute__((ext_vector_type(4))) float f32x4;

#define MFMA(a, b, c) __builtin_amdgcn_mfma_f32_16x16x32_bf16((a), (b), (c), 0, 0, 0)

// ---------------- prep: x -> MFMA A-fragment order, bf16 ----------------
// XAf[t][m(4)][kc(8)][lane*8+e] ; element = x[t][m*16+(l&15)][kc*32+8*(l>>4)+e]
__global__ void xfrag_kernel(const float* __restrict__ x, __hip_bfloat16* __restrict__ xaf) {
    int tid  = blockIdx.x * 256 + threadIdx.x;   // total T*4*8*64 = 1,048,576
    int l    = tid & 63;
    int frag = tid >> 6;                         // t*32 + m*8 + kc
    int kc   = frag & 7;
    int m    = (frag >> 3) & 3;
    int t    = frag >> 5;
    int row  = m * 16 + (l & 15);
    int k0   = kc * 32 + 8 * (l >> 4);
    const float* src = x + ((size_t)(t * NB + row)) * FB + k0;
    __hip_bfloat16* dst = xaf + (size_t)frag * 512 + l * 8;
#pragma unroll
    for (int e = 0; e < 8; ++e) dst[e] = __float2bfloat16(src[e]);
}

// ------------- prep: [Wx;Wh] -> per-(sb,wave) register-load order -------------
// WBf[sb(64)][wv(4)][kcw(10)][g(4)][lane*8+e]
// kc(wv,kcw) = kcw<2 ? wv*2+kcw : 8 + wv*8 + (kcw-2)   (x-chunks spread over waves)
// k = kc*32+8*(l>>4)+e ; s = sb*16+(l&15)
__global__ void wfrag_kernel(const float* __restrict__ Wx, const float* __restrict__ Wh,
                             __hip_bfloat16* __restrict__ wbf) {
    int tid  = blockIdx.x * 256 + threadIdx.x;   // total 64*4*10*4*64 = 655,360
    int l    = tid & 63;
    int frag = tid >> 6;                         // ((sb*4+wv)*10+kcw)*4+g
    int g    = frag & 3;
    int kcw  = (frag >> 2) % 10;
    int wv   = (frag / 40) & 3;
    int sb   = frag / 160;
    int kc   = (kcw < 2) ? (wv * 2 + kcw) : (8 + wv * 8 + (kcw - 2));
    int s    = sb * 16 + (l & 15);
    int k0   = kc * 32 + 8 * (l >> 4);
    __hip_bfloat16* dst = wbf + (size_t)frag * 512 + l * 8;
#pragma unroll
    for (int e = 0; e < 8; ++e) {
        int k = k0 + e;
        float v = (k < FB) ? Wx[((size_t)g * FB + k) * SB + s]
                           : Wh[((size_t)g * SB + (k - FB)) * SB + s];
        dst[e] = __float2bfloat16(v);
    }
}

// ---- init: sentinel-fill hfrag slots 1..3 (3 x 131072 B = 98304 u32) ----
__global__ void sentinit_kernel(unsigned int* __restrict__ p) {
    p[blockIdx.x * 256 + threadIdx.x] = SENT32;
}

// ---------------- persistent LSTM kernel: quarter-row WGs ----------------
// r16 structure + relaxed arrive: |h|<1 so bf16 0x7FC0 (NaN) never occurs in
// data -> sentinel-coded validity. Producer: wave0 computes gates (4 elems/
// thread), issues u64 h-stores then the flag with NO drain/barrier (flag =
// "issued"); consumer: cheap 16-producer flag poll, then loads the 8 fragments
// and RETRIES while any u32 == sentinel. Wave1 re-sentinels the WG's own 512B
// of slot (t+3)&3 each step (ACKed by the next reduce-barrier's vmcnt drain
// BEFORE that slot's next data write & flag -> flag-visible implies sentinel-
// applied implies no stale reads). License dropped: after sync(t) all 64
// same-ng WGs are >= step t-1 > t-3. part[] parity-double-buffered.
__global__ __launch_bounds__(256, 1) void lstm_persist(
    const __hip_bfloat16* __restrict__ xaf,   // [512][4][8][512]
    const __hip_bfloat16* __restrict__ wbf,   // [64][4][10][4][512]
    const float* __restrict__ bias,           // [4][1024]
    __hip_bfloat16* __restrict__ hfrag,       // [4][32][4][512]
    float* __restrict__ cbuf,                 // [64][1024] fp32 c-state
    float* __restrict__ out,                  // [512][64][1024]
    unsigned int* __restrict__ flag,          // [512][256][2] (8B-padded per-WG flags)
    int t0, int nsteps)
{
    __shared__ float part[2][4 * 16 * 4 * 20];  // 2 x 20,480 B (step parity)
    const int tid = threadIdx.x;
    const int wv  = tid >> 6;
    const int l   = tid & 63;
    const int ng  = blockIdx.x >> 6;          // row-group 0..3 (16 rows)
    const int sb  = blockIdx.x & 63;
    const int lr  = l & 15;
    const int lg  = l >> 4;

    // flag poll: lane l -> producer WG (ng, wv*16 + (l&15))  [4-way broadcast]
    const int fidx = (ng * 64 + wv * 16 + (l & 15)) * 2;

    // wave0 gate mapping: thread l -> (row gn4, 4 consecutive s-cols scq..+4)
    const int gn4 = l >> 2;                   // 0..15
    const int scq = (l & 3) * 4;              // 0,4,8,12

    // ---- one-time: weight fragments (stream from L2 every step)
    bf16x8 wf[40];
    {
        const __hip_bfloat16* wp = wbf + ((size_t)(sb * 4 + wv) * 40) * 512 + l * 8;
#pragma unroll
        for (int i = 0; i < 40; ++i) wf[i] = *reinterpret_cast<const bf16x8*>(wp + (size_t)i * 512);
    }
    // ---- one-time: bias + c-state (wave0 only)
    f32x4 brv[4];
    f32x4 creg = {0.f, 0.f, 0.f, 0.f};
    if (wv == 0) {
#pragma unroll
        for (int g = 0; g < 4; ++g)
            brv[g] = *reinterpret_cast<const f32x4*>(&bias[g * SB + sb * 16 + scq]);
        creg = *reinterpret_cast<const f32x4*>(&cbuf[(ng * 16 + gn4) * SB + sb * 16 + scq]);
    }

    f32x4 acc[4];
    // ---- prologue: x-part of first step (h-independent)
#pragma unroll
    for (int g = 0; g < 4; ++g) acc[g] = (f32x4){0.f, 0.f, 0.f, 0.f};
    {
        const __hip_bfloat16* xs = xaf + (size_t)t0 * 16384;
#pragma unroll
        for (int j = 0; j < 2; ++j) {
            int kc = wv * 2 + j;
            bf16x8 a = *reinterpret_cast<const bf16x8*>(xs + (size_t)(ng * 8 + kc) * 512 + l * 8);
#pragma unroll
            for (int g = 0; g < 4; ++g) acc[g] = MFMA(a, wf[j * 4 + g], acc[g]);
        }
    }

    for (int tt = 0; tt < nsteps; ++tt) {
        const int t  = t0 + tt;
        const int pb = t & 1;

        // ---- cheap flag poll: my 16 producers issued step t-1 gates
        if (tt > 0) {
            const unsigned int* f1 = flag + (size_t)(t - 1) * 512;
            for (;;) {
                unsigned a = __hip_atomic_load(&f1[fidx], __ATOMIC_RELAXED, __HIP_MEMORY_SCOPE_AGENT);
                if (__all(a != 0)) break;
            }
            asm volatile("" ::: "memory");
        }

        // ---- load h slices + sentinel verify (retry until all words are data)
        const __hip_bfloat16* hs = hfrag + (size_t)(t & 3) * 65536;
        unsigned long long v[16];
        for (;;) {
#pragma unroll
            for (int j = 0; j < 8; ++j) {
                const unsigned long long* q = reinterpret_cast<const unsigned long long*>(
                    hs + (size_t)((wv * 8 + j) * 4 + ng) * 512 + l * 8);
                v[2 * j]     = __hip_atomic_load(q,     __ATOMIC_RELAXED, __HIP_MEMORY_SCOPE_AGENT);
                v[2 * j + 1] = __hip_atomic_load(q + 1, __ATOMIC_RELAXED, __HIP_MEMORY_SCOPE_AGENT);
            }
            bool ok = true;
#pragma unroll
            for (int k = 0; k < 16; ++k) {
                unsigned lo = (unsigned)v[k], hi = (unsigned)(v[k] >> 32);
                ok = ok && (lo != SENT32) && (hi != SENT32);
            }
            if (__all(ok)) break;
        }
        asm volatile("" ::: "memory");

        // ---- h-part MFMAs straight from the verified registers
#pragma unroll
        for (int j = 0; j < 8; ++j) {
            union { unsigned long long u[2]; bf16x8 a; } ua;
            ua.u[0] = v[2 * j];
            ua.u[1] = v[2 * j + 1];
#pragma unroll
            for (int g = 0; g < 4; ++g) acc[g] = MFMA(ua.a, wf[(2 + j) * 4 + g], acc[g]);
        }

        // ---- cross-wave K-reduce via parity-double-buffered LDS (stride 20)
#pragma unroll
        for (int g = 0; g < 4; ++g)
#pragma unroll
            for (int i = 0; i < 4; ++i)
                part[pb][((wv * 16 + lg * 4 + i) * 4 + g) * 20 + lr] = acc[g][i];
        __syncthreads();   // also ACKs (vmcnt-drains) last step's sentinel/h stores

        if (wv == 0) {
            // ---- gates: 4 elems (gn4, scq..+3); vector LDS reads
            f32x4 z[4];
#pragma unroll
            for (int g = 0; g < 4; ++g) {
                f32x4 s = {0.f, 0.f, 0.f, 0.f};
#pragma unroll
                for (int w2 = 0; w2 < 4; ++w2)
                    s += *reinterpret_cast<const f32x4*>(
                        &part[pb][((w2 * 16 + gn4) * 4 + g) * 20 + scq]);
                z[g] = s + brv[g];
            }
            float hv[4];
            unsigned long long hu = 0;
#pragma unroll
            for (int e = 0; e < 4; ++e) {
                float ig = 1.f / (1.f + expf(-z[0][e]));
                float fg = 1.f / (1.f + expf(-z[1][e]));
                float gg = tanhf(z[2][e]);
                float og = 1.f / (1.f + expf(-z[3][e]));
                float c  = fg * creg[e] + ig * gg;
                float h  = og * tanhf(c);
                creg[e]  = c;
                hv[e]    = h;
                hu |= (unsigned long long)__bfloat16_as_ushort(__float2bfloat16(h)) << (16 * e);
            }
            // h-store: one u64 (4 bf16) at the fragment position
            int k8hi = 2 * (sb & 1) + ((l & 3) >> 1);
            int lane = k8hi * 16 + gn4;
            unsigned long long* hd = reinterpret_cast<unsigned long long*>(
                hfrag + (size_t)((t + 1) & 3) * 65536
                + (size_t)((sb >> 1) * 4 + ng) * 512 + lane * 8) + ((l & 3) & 1);
            __hip_atomic_store(hd, hu, __ATOMIC_RELAXED, __HIP_MEMORY_SCOPE_AGENT);
            asm volatile("" ::: "memory");   // keep flag store after h stores
            if (l == 0)
                __hip_atomic_store(&flag[((size_t)t * 256 + blockIdx.x) * 2], 1u,
                                   __ATOMIC_RELAXED, __HIP_MEMORY_SCOPE_AGENT);
            // out store (off the signal path)
            *reinterpret_cast<f32x4*>(
                &out[(size_t)t * (NB * SB) + (size_t)(ng * 16 + gn4) * SB + sb * 16 + scq])
                = (f32x4){hv[0], hv[1], hv[2], hv[3]};
        } else if (wv == 1) {
            // ---- re-sentinel this WG's own 512B of slot (t+3)&3
            unsigned long long* sp = reinterpret_cast<unsigned long long*>(
                hfrag + (size_t)((t + 3) & 3) * 65536)
                + (size_t)((sb >> 1) * 4 + ng) * 128 + (sb & 1) * 64 + l;
            __hip_atomic_store(sp, SENT64, __ATOMIC_RELAXED, __HIP_MEMORY_SCOPE_AGENT);
        }

        // ---- tail: x-part of next step (h-independent, hides wait latency)
        if (tt + 1 < nsteps) {
#pragma unroll
            for (int g = 0; g < 4; ++g) acc[g] = (f32x4){0.f, 0.f, 0.f, 0.f};
            const __hip_bfloat16* xs = xaf + (size_t)(t + 1) * 16384;
#pragma unroll
            for (int j = 0; j < 2; ++j) {
                int kc = wv * 2 + j;
                bf16x8 a = *reinterpret_cast<const bf16x8*>(xs + (size_t)(ng * 8 + kc) * 512 + l * 8);
#pragma unroll
                for (int g = 0; g < 4; ++g) acc[g] = MFMA(a, wf[j * 4 + g], acc[g]);
            }
        }
    }

    // ---- persist c-state (needed for the per-step fallback path)
    if (wv == 0)
        *reinterpret_cast<f32x4*>(&cbuf[(ng * 16 + gn4) * SB + sb * 16 + scq]) = creg;
}

extern "C" void kernel_launch(void* const* d_in, const int* in_sizes, int n_in,
                              void* d_out, int out_size, void* d_ws, size_t ws_size,
                              hipStream_t stream) {
    const float* x  = (const float*)d_in[0];   // [512][64][256]
    const float* Wx = (const float*)d_in[1];   // [4][256][1024]
    const float* Wh = (const float*)d_in[2];   // [4][1024][1024]
    const float* b  = (const float*)d_in[3];   // [4][1024]
    float* out = (float*)d_out;                // [512][64][1024]

    char* ws = (char*)d_ws;
    __hip_bfloat16* xaf   = (__hip_bfloat16*)ws;                 // 16,777,216 B
    __hip_bfloat16* wbf   = (__hip_bfloat16*)(ws + 16777216);    // 10,485,760 B
    __hip_bfloat16* hfrag = (__hip_bfloat16*)(ws + 27262976);    //    524,288 B (4 slots)
    float*          cbuf  = (float*)(ws + 27787264);             //    262,144 B
    unsigned int*   flag  = (unsigned int*)(ws + 28049408);      //  1,048,576 B

    hipLaunchKernelGGL(xfrag_kernel, dim3(4096), dim3(256), 0, stream, x, xaf);
    hipLaunchKernelGGL(wfrag_kernel, dim3(2560), dim3(256), 0, stream, Wx, Wh, wbf);
    hipMemsetAsync(hfrag, 0, 131072, stream);   // slot 0: h[-1] = 0
    hipLaunchKernelGGL(sentinit_kernel, dim3(384), dim3(256), 0, stream,
                       (unsigned int*)(hfrag + 65536));  // slots 1..3 = sentinel
    hipMemsetAsync(cbuf, 0, 262144, stream);    // c[-1] = 0
    hipMemsetAsync(flag, 0, 1048576, stream);   // per-step per-WG flags

    const __hip_bfloat16* p_xaf = xaf;
    const __hip_bfloat16* p_wbf = wbf;
    const float* p_bias = b;
    __hip_bfloat16* p_hfrag = hfrag;
    float* p_cbuf = cbuf;
    float* p_out = out;
    unsigned int* p_flag = flag;
    int z0 = 0, ns = T_LEN;
    void* args[] = {&p_xaf, &p_wbf, &p_bias, &p_hfrag, &p_cbuf, &p_out, &p_flag, &z0, &ns};
    hipError_t err = hipLaunchCooperativeKernel((void*)lstm_persist, dim3(NWG), dim3(256),
                                                args, 0, stream);
    if (err != hipSuccess) {
        // fallback: per-step plain launches (kernel boundaries order memory;
        // polls pass immediately on prior-launch data)
        for (int t = 0; t < T_LEN; ++t) {
            hipLaunchKernelGGL(lstm_persist, dim3(NWG), dim3(256), 0, stream,
                               xaf, wbf, b, hfrag, cbuf, out, flag, t, 1);
        }
    }
}

// Round 19
// 1522.265 us; speedup vs baseline: 1.6105x; 1.6105x over previous
//
#include <hip/hip_runtime.h>
#include <hip/hip_bf16.h>

#define T_LEN 512
#define NB 64      // batch
#define FB 256     // input features
#define SB 1024    // hidden size
#define NWG 256    // persistent workgroups: (ng 0..3) x (sb 0..63)

typedef __attribute__((ext_vector_type(8))) short bf16x8;
typedef __attribute__((ext_vector_type(4))) float f32x4;
typedef __attribute__((ext_vector_type(2))) float f32x2;

#define MFMA(a, b, c) __builtin_amdgcn_mfma_f32_16x16x32_bf16((a), (b), (c), 0, 0, 0)

// device-scope (sc1) 16B fragment load as 2 relaxed agent u64 atomics
__device__ __forceinline__ bf16x8 load_frag_dev(const __hip_bfloat16* p) {
    const unsigned long long* q = (const unsigned long long*)p;
    unsigned long long a = __hip_atomic_load(q,     __ATOMIC_RELAXED, __HIP_MEMORY_SCOPE_AGENT);
    unsigned long long b = __hip_atomic_load(q + 1, __ATOMIC_RELAXED, __HIP_MEMORY_SCOPE_AGENT);
    union { unsigned long long u[2]; bf16x8 v; } r;
    r.u[0] = a; r.u[1] = b;
    return r.v;
}

// ---------------- prep: x -> MFMA A-fragment order, bf16 ----------------
// XAf[t][m(4)][kc(8)][lane*8+e] ; element = x[t][m*16+(l&15)][kc*32+8*(l>>4)+e]
__global__ void xfrag_kernel(const float* __restrict__ x, __hip_bfloat16* __restrict__ xaf) {
    int tid  = blockIdx.x * 256 + threadIdx.x;   // total T*4*8*64 = 1,048,576
    int l    = tid & 63;
    int frag = tid >> 6;                         // t*32 + m*8 + kc
    int kc   = frag & 7;
    int m    = (frag >> 3) & 3;
    int t    = frag >> 5;
    int row  = m * 16 + (l & 15);
    int k0   = kc * 32 + 8 * (l >> 4);
    const float* src = x + ((size_t)(t * NB + row)) * FB + k0;
    __hip_bfloat16* dst = xaf + (size_t)frag * 512 + l * 8;
#pragma unroll
    for (int e = 0; e < 8; ++e) dst[e] = __float2bfloat16(src[e]);
}

// ------------- prep: [Wx;Wh] -> per-(sb,wave) register-load order -------------
// WBf[sb(64)][wv(4)][kcw(10)][g(4)][lane*8+e]
// kc(wv,kcw) = kcw<2 ? wv*2+kcw : 8 + wv*8 + (kcw-2)   (x-chunks spread over waves)
// k = kc*32+8*(l>>4)+e ; s = sb*16+(l&15)
__global__ void wfrag_kernel(const float* __restrict__ Wx, const float* __restrict__ Wh,
                             __hip_bfloat16* __restrict__ wbf) {
    int tid  = blockIdx.x * 256 + threadIdx.x;   // total 64*4*10*4*64 = 655,360
    int l    = tid & 63;
    int frag = tid >> 6;                         // ((sb*4+wv)*10+kcw)*4+g
    int g    = frag & 3;
    int kcw  = (frag >> 2) % 10;
    int wv   = (frag / 40) & 3;
    int sb   = frag / 160;
    int kc   = (kcw < 2) ? (wv * 2 + kcw) : (8 + wv * 8 + (kcw - 2));
    int s    = sb * 16 + (l & 15);
    int k0   = kc * 32 + 8 * (l >> 4);
    __hip_bfloat16* dst = wbf + (size_t)frag * 512 + l * 8;
#pragma unroll
    for (int e = 0; e < 8; ++e) {
        int k = k0 + e;
        float v = (k < FB) ? Wx[((size_t)g * FB + k) * SB + s]
                           : Wh[((size_t)g * SB + (k - FB)) * SB + s];
        dst[e] = __float2bfloat16(v);
    }
}

// ---------------- persistent LSTM kernel: quarter-row WGs ----------------
// r16 structure (1568 us), TWO latency-path deltas:
// (1) t-3 license REMOVED -- provably redundant: the 4 waves' t-1 polls cover
//     all 64 same-ng WGs, and the reduce-barrier joins them before any thread
//     overwrites slot (t+1)&3 = (t-3)&3; flagging t-1 implies done reading t-3.
// (2) out-stores moved AFTER the arrive barrier + flag -- they no longer sit
//     in the pre-flag vmcnt drain (HBM-store ACKs were on the signal path).
__global__ __launch_bounds__(256, 1) void lstm_persist(
    const __hip_bfloat16* __restrict__ xaf,   // [512][4][8][512]
    const __hip_bfloat16* __restrict__ wbf,   // [64][4][10][4][512]
    const float* __restrict__ bias,           // [4][1024]
    __hip_bfloat16* __restrict__ hfrag,       // [4][32][4][512]
    float* __restrict__ cbuf,                 // [64][1024] fp32 c-state
    float* __restrict__ out,                  // [512][64][1024]
    unsigned int* __restrict__ flag,          // [512][256][2] (8B-padded per-WG flags)
    int t0, int nsteps, int use_sync)
{
    __shared__ float part[4 * 16 * 4 * 17];   // 17,408 B: ((wv*16+n)*4+g)*17 + sc
    const int tid = threadIdx.x;
    const int wv  = tid >> 6;
    const int l   = tid & 63;
    const int ng  = blockIdx.x >> 6;          // row-group 0..3 (16 rows)
    const int sb  = blockIdx.x & 63;
    const int lr  = l & 15;
    const int lg  = l >> 4;

    // t-1 poll: lane l -> producer WG (ng, wv*16 + (l&15))  [4-way broadcast]
    const int fidx = (ng * 64 + wv * 16 + (l & 15)) * 2;

    // gate-phase mapping (threads 0..127): thread -> (row gn, 2 consecutive s-cols)
    const int gact = (tid < 128);
    const int gn   = (tid >> 3) & 15;         // 0..15 local row
    const int sc0  = (tid & 7) * 2;           // 0,2,..,14

    // ---- one-time: weight fragment pointers (stream from L2 every step)
    bf16x8 wf[40];
    {
        const __hip_bfloat16* wp = wbf + ((size_t)(sb * 4 + wv) * 40) * 512 + l * 8;
#pragma unroll
        for (int i = 0; i < 40; ++i) wf[i] = *reinterpret_cast<const bf16x8*>(wp + (size_t)i * 512);
    }
    // ---- one-time: bias + c-state for this thread's (gn, sc0..sc0+1)
    float br[8];
    f32x2 creg = {0.f, 0.f};
    if (gact) {
#pragma unroll
        for (int g = 0; g < 4; ++g) {
            br[g * 2]     = bias[g * SB + sb * 16 + sc0];
            br[g * 2 + 1] = bias[g * SB + sb * 16 + sc0 + 1];
        }
        creg = *reinterpret_cast<const f32x2*>(
            &cbuf[(ng * 16 + gn) * SB + sb * 16 + sc0]);
    }

    f32x4 acc[4];
    // ---- prologue: x-part of first step (h-independent)
#pragma unroll
    for (int g = 0; g < 4; ++g) acc[g] = (f32x4){0.f, 0.f, 0.f, 0.f};
    {
        const __hip_bfloat16* xs = xaf + (size_t)t0 * 16384;
#pragma unroll
        for (int j = 0; j < 2; ++j) {
            int kc = wv * 2 + j;
            bf16x8 a = *reinterpret_cast<const bf16x8*>(xs + (size_t)(ng * 8 + kc) * 512 + l * 8);
#pragma unroll
            for (int g = 0; g < 4; ++g) acc[g] = MFMA(a, wf[j * 4 + g], acc[g]);
        }
    }

    for (int tt = 0; tt < nsteps; ++tt) {
        const int t = t0 + tt;

        if (use_sync && tt > 0) {
            // critical wait: my 16 producers arrived at t-1 (h[t] cols ready).
            // (No license needed: these polls + the reduce barrier cover all 64
            //  same-ng WGs at >= t-1 before slot (t-3)&3 is overwritten.)
            const unsigned int* f1 = flag + (size_t)(t - 1) * 512;
            for (;;) {
                unsigned a = __hip_atomic_load(&f1[fidx], __ATOMIC_RELAXED, __HIP_MEMORY_SCOPE_AGENT);
                if (__all(a != 0)) break;
            }
            asm volatile("" ::: "memory");   // no load motion across the wait
        }

        // ---- h-part MFMAs (8 sc1 fragment loads, compiler-batched)
        const __hip_bfloat16* hs = hfrag + (size_t)(t & 3) * 65536;
#pragma unroll
        for (int j = 0; j < 8; ++j) {
            int kch = wv * 8 + j;
            bf16x8 a = load_frag_dev(hs + (size_t)(kch * 4 + ng) * 512 + l * 8);
#pragma unroll
            for (int g = 0; g < 4; ++g) acc[g] = MFMA(a, wf[(2 + j) * 4 + g], acc[g]);
        }

        // ---- cross-wave K-reduce via LDS
#pragma unroll
        for (int g = 0; g < 4; ++g)
#pragma unroll
            for (int i = 0; i < 4; ++i)
                part[((wv * 16 + lg * 4 + i) * 4 + g) * 17 + lr] = acc[g][i];
        __syncthreads();

        // ---- gates + state update: threads 0..127, (gn, sc0..sc0+1)
        float hv0 = 0.f, hv1 = 0.f;
        if (gact) {
            float z[4][2];
#pragma unroll
            for (int g = 0; g < 4; ++g) {
                float s0 = 0.f, s1 = 0.f;
#pragma unroll
                for (int w2 = 0; w2 < 4; ++w2) {
                    const float* pr = &part[((w2 * 16 + gn) * 4 + g) * 17 + sc0];
                    s0 += pr[0];
                    s1 += pr[1];
                }
                z[g][0] = s0 + br[g * 2];
                z[g][1] = s1 + br[g * 2 + 1];
            }
            float hv[2];
#pragma unroll
            for (int e = 0; e < 2; ++e) {
                float ig = 1.f / (1.f + expf(-z[0][e]));
                float fg = 1.f / (1.f + expf(-z[1][e]));
                float gg = tanhf(z[2][e]);
                float og = 1.f / (1.f + expf(-z[3][e]));
                float c  = fg * creg[e] + ig * gg;
                hv[e]    = og * tanhf(c);
                creg[e]  = c;
            }
            hv0 = hv[0]; hv1 = hv[1];
            // h-frag: one device-scope u32 store (2 packed bf16) -- the ONLY
            // store in the pre-flag drain
            unsigned u0 = (unsigned)__bfloat16_as_ushort(__float2bfloat16(hv0));
            unsigned u1 = (unsigned)__bfloat16_as_ushort(__float2bfloat16(hv1));
            int sg0  = sb * 16 + sc0;
            int kch  = sg0 >> 5;
            int k8   = sg0 & 31;
            int lane = (k8 >> 3) * 16 + gn;   // row within this WG's m-tile = gn
            unsigned int* hd = reinterpret_cast<unsigned int*>(
                hfrag + (size_t)((t + 1) & 3) * 65536
                + (size_t)(kch * 4 + ng) * 512 + lane * 8 + (k8 & 7));
            __hip_atomic_store(hd, u0 | (u1 << 16), __ATOMIC_RELAXED, __HIP_MEMORY_SCOPE_AGENT);
        }

        // ---- arrive: barrier drains h-stores (only), then tid0 flag
        if (use_sync) {
            __syncthreads();
            if (tid == 0)
                __hip_atomic_store(&flag[((size_t)t * 256 + blockIdx.x) * 2], 1u,
                                   __ATOMIC_RELAXED, __HIP_MEMORY_SCOPE_AGENT);
        }

        // ---- out-store AFTER the flag (off the signal path; drains in background)
        if (gact) {
            *reinterpret_cast<f32x2*>(
                &out[(size_t)t * (NB * SB) + (size_t)(ng * 16 + gn) * SB + sb * 16 + sc0])
                = (f32x2){hv0, hv1};
        }

        // ---- tail: x-part of next step (h-independent, hides wait latency)
        if (tt + 1 < nsteps) {
#pragma unroll
            for (int g = 0; g < 4; ++g) acc[g] = (f32x4){0.f, 0.f, 0.f, 0.f};
            const __hip_bfloat16* xs = xaf + (size_t)(t + 1) * 16384;
#pragma unroll
            for (int j = 0; j < 2; ++j) {
                int kc = wv * 2 + j;
                bf16x8 a = *reinterpret_cast<const bf16x8*>(xs + (size_t)(ng * 8 + kc) * 512 + l * 8);
#pragma unroll
                for (int g = 0; g < 4; ++g) acc[g] = MFMA(a, wf[j * 4 + g], acc[g]);
            }
        }
    }

    // ---- persist c-state (needed for the per-step fallback path)
    if (gact)
        *reinterpret_cast<f32x2*>(&cbuf[(ng * 16 + gn) * SB + sb * 16 + sc0]) = creg;
}

extern "C" void kernel_launch(void* const* d_in, const int* in_sizes, int n_in,
                              void* d_out, int out_size, void* d_ws, size_t ws_size,
                              hipStream_t stream) {
    const float* x  = (const float*)d_in[0];   // [512][64][256]
    const float* Wx = (const float*)d_in[1];   // [4][256][1024]
    const float* Wh = (const float*)d_in[2];   // [4][1024][1024]
    const float* b  = (const float*)d_in[3];   // [4][1024]
    float* out = (float*)d_out;                // [512][64][1024]

    char* ws = (char*)d_ws;
    __hip_bfloat16* xaf   = (__hip_bfloat16*)ws;                 // 16,777,216 B
    __hip_bfloat16* wbf   = (__hip_bfloat16*)(ws + 16777216);    // 10,485,760 B
    __hip_bfloat16* hfrag = (__hip_bfloat16*)(ws + 27262976);    //    524,288 B (4 bufs)
    float*          cbuf  = (float*)(ws + 27787264);             //    262,144 B
    unsigned int*   flag  = (unsigned int*)(ws + 28049408);      //  1,048,576 B

    hipLaunchKernelGGL(xfrag_kernel, dim3(4096), dim3(256), 0, stream, x, xaf);
    hipLaunchKernelGGL(wfrag_kernel, dim3(2560), dim3(256), 0, stream, Wx, Wh, wbf);
    hipMemsetAsync(hfrag, 0, 524288, stream);   // h[-1] = 0
    hipMemsetAsync(cbuf, 0, 262144, stream);    // c[-1] = 0
    hipMemsetAsync(flag, 0, 1048576, stream);   // per-step per-WG flags

    const __hip_bfloat16* p_xaf = xaf;
    const __hip_bfloat16* p_wbf = wbf;
    const float* p_bias = b;
    __hip_bfloat16* p_hfrag = hfrag;
    float* p_cbuf = cbuf;
    float* p_out = out;
    unsigned int* p_flag = flag;
    int z0 = 0, ns = T_LEN, us = 1;
    void* args[] = {&p_xaf, &p_wbf, &p_bias, &p_hfrag, &p_cbuf, &p_out, &p_flag, &z0, &ns, &us};
    hipError_t err = hipLaunchCooperativeKernel((void*)lstm_persist, dim3(NWG), dim3(256),
                                                args, 0, stream);
    if (err != hipSuccess) {
        // fallback: per-step plain launches (kernel boundaries order memory)
        for (int t = 0; t < T_LEN; ++t) {
            hipLaunchKernelGGL(lstm_persist, dim3(NWG), dim3(256), 0, stream,
                               xaf, wbf, b, hfrag, cbuf, out, flag, t, 1, 0);
        }
    }
}